// Round 1
// baseline (13612.793 us; speedup 1.0000x reference)
//
#include <hip/hip_runtime.h>
#include <math.h>

#define Hn 50
#define Dn 8
#define Tn 512
#define BB 4          // batch rows per block
#define NBLK (2048 / BB)

__device__ __forceinline__ float sigmoidf_(float x) {
    return 1.0f / (1.0f + __expf(-x));
}
__device__ __forceinline__ float tanhf_(float x) {
    float a = fabsf(x);
    float e = __expf(-2.0f * a);
    float r = (1.0f - e) / (1.0f + e);
    return copysignf(r, x);
}

// Persistent 2-layer LSTM. Each thread owns one padded gate row
// (gate = tid>>6 in {i,f,g,o}, cell = tid&63; cell>=50 is zero padding)
// and keeps its weight rows in VGPRs for the whole sequence.
__global__ __launch_bounds__(256, 2) void lstm2_kernel(
    const float* __restrict__ x,
    const float* __restrict__ Wih0, const float* __restrict__ Whh0,
    const float* __restrict__ bih0, const float* __restrict__ bhh0,
    const float* __restrict__ Wih1, const float* __restrict__ Whh1,
    const float* __restrict__ bih1, const float* __restrict__ bhh1,
    const float* __restrict__ Wlin, const float* __restrict__ blin,
    float* __restrict__ out)
{
    const int tid = threadIdx.x;      // 0..255
    const int b0 = blockIdx.x * BB;   // batch base for this block
    const int gate = tid >> 6;        // 0..3  (i,f,g,o)
    const int cell = tid & 63;        // 0..63 (50..63 = padding)
    const bool real = (cell < Hn);
    const int grow = gate * Hn + cell; // real weight row (valid iff real)

    __shared__ __align__(16) float h0s[Hn][BB];
    __shared__ __align__(16) float h1s[Hn][BB];
    __shared__ __align__(16) float g0s[256][BB];
    __shared__ __align__(16) float g1s[256][BB];
    __shared__ __align__(16) float xss[2][BB][Dn];  // double-buffered x_t stage

    // ---- weight rows in registers (persistent across all 512 steps) ----
    float wx[Dn], wa[Hn], wb[Hn], wc[Hn];
    float bias0 = 0.f, bias1 = 0.f;
    if (real) {
        #pragma unroll
        for (int d = 0; d < Dn; ++d) wx[d] = Wih0[grow * Dn + d];
        #pragma unroll
        for (int k = 0; k < Hn; ++k) {
            wa[k] = Whh0[grow * Hn + k];   // layer0 recurrent
            wb[k] = Wih1[grow * Hn + k];   // layer1 input
            wc[k] = Whh1[grow * Hn + k];   // layer1 recurrent
        }
        bias0 = bih0[grow] + bhh0[grow];
        bias1 = bih1[grow] + bhh1[grow];
    } else {
        #pragma unroll
        for (int d = 0; d < Dn; ++d) wx[d] = 0.f;
        #pragma unroll
        for (int k = 0; k < Hn; ++k) { wa[k] = 0.f; wb[k] = 0.f; wc[k] = 0.f; }
    }

    // ---- activation-task mapping: 200 threads own one (cell,b) state ----
    const int cellA = tid >> 2;       // 0..63 (valid 0..49)
    const int bA = tid & 3;
    const bool actT = (tid < Hn * BB);  // 200 state-owning threads
    float c0 = 0.f, c1 = 0.f;           // cell state lives in registers

    if (actT) { h0s[cellA][bA] = 0.f; h1s[cellA][bA] = 0.f; }
    // stage x for t=0
    if (tid < 8) {
        const float4 v = *(const float4*)(x + (size_t)(b0 + (tid >> 1)) * Tn * Dn
                                            + (size_t)(tid & 1) * 4);
        *(float4*)&xss[0][tid >> 1][(tid & 1) * 4] = v;
    }
    __syncthreads();

    for (int t = 0; t < Tn; ++t) {
        const int p = t & 1;

        // ---- phase 1: accA = Wih0*x_t + Whh0*h0 + b0 ; accC = Whh1*h1 ----
        float accA[BB], accC[BB];
        #pragma unroll
        for (int b = 0; b < BB; ++b) { accA[b] = bias0; accC[b] = 0.f; }
        #pragma unroll
        for (int b = 0; b < BB; ++b) {
            const float4 xa = *(const float4*)&xss[p][b][0];
            const float4 xb = *(const float4*)&xss[p][b][4];
            accA[b] += wx[0]*xa.x + wx[1]*xa.y + wx[2]*xa.z + wx[3]*xa.w
                     + wx[4]*xb.x + wx[5]*xb.y + wx[6]*xb.z + wx[7]*xb.w;
        }
        #pragma unroll
        for (int k = 0; k < Hn; ++k) {
            const float4 hv0 = *(const float4*)&h0s[k][0];  // broadcast read
            const float4 hv1 = *(const float4*)&h1s[k][0];
            accA[0] += wa[k] * hv0.x; accA[1] += wa[k] * hv0.y;
            accA[2] += wa[k] * hv0.z; accA[3] += wa[k] * hv0.w;
            accC[0] += wc[k] * hv1.x; accC[1] += wc[k] * hv1.y;
            accC[2] += wc[k] * hv1.z; accC[3] += wc[k] * hv1.w;
        }
        *(float4*)&g0s[tid][0] = make_float4(accA[0], accA[1], accA[2], accA[3]);
        __syncthreads();

        // ---- layer-0 activations ----
        if (actT) {
            const float gi = g0s[cellA][bA];
            const float gf = g0s[64 + cellA][bA];
            const float gg = g0s[128 + cellA][bA];
            const float go = g0s[192 + cellA][bA];
            const float iv = sigmoidf_(gi);
            const float fv = sigmoidf_(gf);
            const float gv = tanhf_(gg);
            const float ov = sigmoidf_(go);
            c0 = fv * c0 + iv * gv;
            h0s[cellA][bA] = ov * tanhf_(c0);
        }
        __syncthreads();

        // ---- phase 2: accB = Wih1*h0_new + accC + b1 ----
        float accB[BB];
        #pragma unroll
        for (int b = 0; b < BB; ++b) accB[b] = accC[b] + bias1;
        #pragma unroll
        for (int k = 0; k < Hn; ++k) {
            const float4 hv0 = *(const float4*)&h0s[k][0];
            accB[0] += wb[k] * hv0.x; accB[1] += wb[k] * hv0.y;
            accB[2] += wb[k] * hv0.z; accB[3] += wb[k] * hv0.w;
        }
        *(float4*)&g1s[tid][0] = make_float4(accB[0], accB[1], accB[2], accB[3]);
        __syncthreads();

        // ---- layer-1 activations + x prefetch for t+1 ----
        if (actT) {
            const float gi = g1s[cellA][bA];
            const float gf = g1s[64 + cellA][bA];
            const float gg = g1s[128 + cellA][bA];
            const float go = g1s[192 + cellA][bA];
            const float iv = sigmoidf_(gi);
            const float fv = sigmoidf_(gf);
            const float gv = tanhf_(gg);
            const float ov = sigmoidf_(go);
            c1 = fv * c1 + iv * gv;
            h1s[cellA][bA] = ov * tanhf_(c1);
        }
        if (tid >= 248 && t + 1 < Tn) {   // idle lanes of wave 3 prefetch x
            const int i = tid - 248;      // 0..7
            const float4 v = *(const float4*)(x + (size_t)(b0 + (i >> 1)) * Tn * Dn
                                                + (size_t)(t + 1) * Dn
                                                + (size_t)(i & 1) * 4);
            *(float4*)&xss[(t + 1) & 1][i >> 1][(i & 1) * 4] = v;
        }
        __syncthreads();
    }

    // ---- head: out[b] = h1_last . Wlin + blin ----
    if (tid < BB) {
        float o = blin[0];
        #pragma unroll
        for (int k = 0; k < Hn; ++k) o += Wlin[k] * h1s[k][tid];
        out[b0 + tid] = o;
    }
}

extern "C" void kernel_launch(void* const* d_in, const int* in_sizes, int n_in,
                              void* d_out, int out_size, void* d_ws, size_t ws_size,
                              hipStream_t stream) {
    const float* x    = (const float*)d_in[0];
    const float* Wih0 = (const float*)d_in[1];
    const float* Whh0 = (const float*)d_in[2];
    const float* bih0 = (const float*)d_in[3];
    const float* bhh0 = (const float*)d_in[4];
    const float* Wih1 = (const float*)d_in[5];
    const float* Whh1 = (const float*)d_in[6];
    const float* bih1 = (const float*)d_in[7];
    const float* bhh1 = (const float*)d_in[8];
    const float* Wlin = (const float*)d_in[9];
    const float* blin = (const float*)d_in[10];
    float* out = (float*)d_out;

    lstm2_kernel<<<NBLK, 256, 0, stream>>>(x, Wih0, Whh0, bih0, bhh0,
                                           Wih1, Whh1, bih1, bhh1,
                                           Wlin, blin, out);
}

// Round 2
// 4928.007 us; speedup vs baseline: 2.7623x; 2.7623x over previous
//
#include <hip/hip_runtime.h>
#include <math.h>

#define Hn 50
#define Dn 8
#define Tn 512
#define BB 8            // batch rows per block
#define KH 25           // k-range per thread half
#define NBLK (2048 / BB)

__device__ __forceinline__ float sigmoidf_(float x) {
    return 1.0f / (1.0f + __expf(-x));
}
__device__ __forceinline__ float tanhf_(float x) {
    float a = fabsf(x);
    float e = __expf(-2.0f * a);
    float r = (1.0f - e) / (1.0f + e);
    return copysignf(r, x);
}

// Persistent 2-layer LSTM, k-split to keep weights in VGPRs without spills.
// 512 threads: half = tid>>8, rid = tid&255 (gate = rid>>6, cell = rid&63,
// cells 50..63 are padding). Each thread holds 25 of 50 k's of its gate-row
// for Whh0/Wih1/Whh1 (+4 of 8 Wih0 cols) = 79 weight floats in registers.
// Activation threads (tid = bA*64 + cellA) combine the two half-partials.
__global__ __launch_bounds__(512, 2) void lstm2_kernel(
    const float* __restrict__ x,
    const float* __restrict__ Wih0, const float* __restrict__ Whh0,
    const float* __restrict__ bih0, const float* __restrict__ bhh0,
    const float* __restrict__ Wih1, const float* __restrict__ Whh1,
    const float* __restrict__ bih1, const float* __restrict__ bhh1,
    const float* __restrict__ Wlin, const float* __restrict__ blin,
    float* __restrict__ out)
{
    const int tid  = threadIdx.x;        // 0..511
    const int b0   = blockIdx.x * BB;
    const int half = tid >> 8;           // 0,1 : k in [half*25, half*25+25)
    const int rid  = tid & 255;
    const int gate = rid >> 6;           // 0..3 (i,f,g,o)
    const int cell = rid & 63;           // 0..63 (50..63 padding)
    const bool real = (cell < Hn);
    const int grow = gate * Hn + cell;   // weight row (valid iff real)
    const int k0   = half * KH;

    __shared__ __align__(16) float h0s[Hn][BB];
    __shared__ __align__(16) float h1s[Hn][BB];
    __shared__ __align__(16) float gP[2][BB][256];  // [half][b][rid] partials
    __shared__ __align__(16) float xss[2][BB][Dn];  // double-buffered x_t

    // ---- per-thread weight slices in registers ----
    float wa[KH], wb[KH], wc[KH], wx[4];
    if (real) {
        #pragma unroll
        for (int j = 0; j < KH; ++j) {
            wa[j] = Whh0[grow * Hn + k0 + j];
            wb[j] = Wih1[grow * Hn + k0 + j];
            wc[j] = Whh1[grow * Hn + k0 + j];
        }
        #pragma unroll
        for (int d = 0; d < 4; ++d) wx[d] = Wih0[grow * Dn + half * 4 + d];
    } else {
        #pragma unroll
        for (int j = 0; j < KH; ++j) { wa[j] = 0.f; wb[j] = 0.f; wc[j] = 0.f; }
        #pragma unroll
        for (int d = 0; d < 4; ++d) wx[d] = 0.f;
    }

    // ---- activation mapping: thread (bA, cellA) owns state (cellA, bA) ----
    const int bA    = tid >> 6;          // 0..7 (wave index)
    const int cellA = tid & 63;          // 0..63 (50..63 idle)
    const bool actT = (cellA < Hn);
    float bs0[4], bs1[4];
    if (actT) {
        #pragma unroll
        for (int g = 0; g < 4; ++g) {
            bs0[g] = bih0[g * Hn + cellA] + bhh0[g * Hn + cellA];
            bs1[g] = bih1[g * Hn + cellA] + bhh1[g * Hn + cellA];
        }
        h0s[cellA][bA] = 0.f;
        h1s[cellA][bA] = 0.f;
    }
    float c0 = 0.f, c1 = 0.f;

    // stage x for t=0 (8 rows x 2 float4)
    if (tid < 16) {
        const int row = tid >> 1, part = tid & 1;
        const float4 v = *(const float4*)(x + (size_t)(b0 + row) * Tn * Dn
                                            + (size_t)part * 4);
        *(float4*)&xss[0][row][part * 4] = v;
    }
    __syncthreads();

    const bool pfT = (tid >= 498 && tid < 506);  // wave-7 padding threads
    const int pfRow = tid - 498;

    for (int t = 0; t < Tn; ++t) {
        const int p = t & 1;

        // issue x(t+1) prefetch early (wave-7 padding threads)
        float4 xp0, xp1;
        if (pfT && t + 1 < Tn) {
            const float* xr = x + (size_t)(b0 + pfRow) * Tn * Dn
                                + (size_t)(t + 1) * Dn;
            xp0 = *(const float4*)xr;
            xp1 = *(const float4*)(xr + 4);
        }

        // ---- phase 1: partial accA = wx.x_t + wa.h0 ; partial accC = wc.h1 ----
        float accA[BB], accC[BB];
        #pragma unroll
        for (int b = 0; b < BB; ++b) {
            const float4 xv = *(const float4*)&xss[p][b][half * 4];
            accA[b] = wx[0]*xv.x + wx[1]*xv.y + wx[2]*xv.z + wx[3]*xv.w;
            accC[b] = 0.f;
        }
        #pragma unroll
        for (int j = 0; j < KH; ++j) {
            const int k = k0 + j;
            const float4 h0lo = *(const float4*)&h0s[k][0];   // broadcast
            const float4 h0hi = *(const float4*)&h0s[k][4];
            const float4 h1lo = *(const float4*)&h1s[k][0];
            const float4 h1hi = *(const float4*)&h1s[k][4];
            accA[0] += wa[j]*h0lo.x; accA[1] += wa[j]*h0lo.y;
            accA[2] += wa[j]*h0lo.z; accA[3] += wa[j]*h0lo.w;
            accA[4] += wa[j]*h0hi.x; accA[5] += wa[j]*h0hi.y;
            accA[6] += wa[j]*h0hi.z; accA[7] += wa[j]*h0hi.w;
            accC[0] += wc[j]*h1lo.x; accC[1] += wc[j]*h1lo.y;
            accC[2] += wc[j]*h1lo.z; accC[3] += wc[j]*h1lo.w;
            accC[4] += wc[j]*h1hi.x; accC[5] += wc[j]*h1hi.y;
            accC[6] += wc[j]*h1hi.z; accC[7] += wc[j]*h1hi.w;
        }
        #pragma unroll
        for (int b = 0; b < BB; ++b) gP[half][b][rid] = accA[b];  // stride-1
        __syncthreads();

        // ---- layer-0 activations (gates = halves summed + bias) ----
        if (actT) {
            const float gi = gP[0][bA][      cellA] + gP[1][bA][      cellA] + bs0[0];
            const float gf = gP[0][bA][ 64 + cellA] + gP[1][bA][ 64 + cellA] + bs0[1];
            const float gg = gP[0][bA][128 + cellA] + gP[1][bA][128 + cellA] + bs0[2];
            const float go = gP[0][bA][192 + cellA] + gP[1][bA][192 + cellA] + bs0[3];
            const float iv = sigmoidf_(gi);
            const float fv = sigmoidf_(gf);
            const float gv = tanhf_(gg);
            const float ov = sigmoidf_(go);
            c0 = fv * c0 + iv * gv;
            h0s[cellA][bA] = ov * tanhf_(c0);
        }
        __syncthreads();

        // ---- phase 2: accC += wb . h0_new  (partial gates for layer 1) ----
        #pragma unroll
        for (int j = 0; j < KH; ++j) {
            const int k = k0 + j;
            const float4 h0lo = *(const float4*)&h0s[k][0];
            const float4 h0hi = *(const float4*)&h0s[k][4];
            accC[0] += wb[j]*h0lo.x; accC[1] += wb[j]*h0lo.y;
            accC[2] += wb[j]*h0lo.z; accC[3] += wb[j]*h0lo.w;
            accC[4] += wb[j]*h0hi.x; accC[5] += wb[j]*h0hi.y;
            accC[6] += wb[j]*h0hi.z; accC[7] += wb[j]*h0hi.w;
        }
        #pragma unroll
        for (int b = 0; b < BB; ++b) gP[half][b][rid] = accC[b];
        __syncthreads();

        // ---- layer-1 activations + x(t+1) stage ----
        if (actT) {
            const float gi = gP[0][bA][      cellA] + gP[1][bA][      cellA] + bs1[0];
            const float gf = gP[0][bA][ 64 + cellA] + gP[1][bA][ 64 + cellA] + bs1[1];
            const float gg = gP[0][bA][128 + cellA] + gP[1][bA][128 + cellA] + bs1[2];
            const float go = gP[0][bA][192 + cellA] + gP[1][bA][192 + cellA] + bs1[3];
            const float iv = sigmoidf_(gi);
            const float fv = sigmoidf_(gf);
            const float gv = tanhf_(gg);
            const float ov = sigmoidf_(go);
            c1 = fv * c1 + iv * gv;
            h1s[cellA][bA] = ov * tanhf_(c1);
        }
        if (pfT && t + 1 < Tn) {
            *(float4*)&xss[(t + 1) & 1][pfRow][0] = xp0;
            *(float4*)&xss[(t + 1) & 1][pfRow][4] = xp1;
        }
        __syncthreads();
    }

    // ---- head: out[b] = h1_last . Wlin + blin ----
    if (tid < BB) {
        float o = blin[0];
        #pragma unroll
        for (int k = 0; k < Hn; ++k) o += Wlin[k] * h1s[k][tid];
        out[b0 + tid] = o;
    }
}

extern "C" void kernel_launch(void* const* d_in, const int* in_sizes, int n_in,
                              void* d_out, int out_size, void* d_ws, size_t ws_size,
                              hipStream_t stream) {
    const float* x    = (const float*)d_in[0];
    const float* Wih0 = (const float*)d_in[1];
    const float* Whh0 = (const float*)d_in[2];
    const float* bih0 = (const float*)d_in[3];
    const float* bhh0 = (const float*)d_in[4];
    const float* Wih1 = (const float*)d_in[5];
    const float* Whh1 = (const float*)d_in[6];
    const float* bih1 = (const float*)d_in[7];
    const float* bhh1 = (const float*)d_in[8];
    const float* Wlin = (const float*)d_in[9];
    const float* blin = (const float*)d_in[10];
    float* out = (float*)d_out;

    lstm2_kernel<<<NBLK, 512, 0, stream>>>(x, Wih0, Whh0, bih0, bhh0,
                                           Wih1, Whh1, bih1, bhh1,
                                           Wlin, blin, out);
}